// Round 6
// baseline (8066.066 us; speedup 1.0000x reference)
//
#include <hip/hip_runtime.h>

// Problem constants (from setup_inputs: B=16, N=16384, D=128, S=N/4)
#define BATCH    16
#define NPTS     16384
#define NSAMP    4096
#define NTHREADS 1024
#define PPT      16      // NPTS / NTHREADS, strided: thread t owns {k*1024+t}

// DPP move helper (disabled lanes keep old value = own value)
template<int CTRL, int RM>
__device__ __forceinline__ float dpp_movf(float v) {
    return __int_as_float(__builtin_amdgcn_update_dpp(
        __float_as_int(v), __float_as_int(v), CTRL, RM, 0xF, false));
}

// -----------------------------------------------------------------------------
// FPS kernel: one block per batch, 1024 threads.
// x,y live in LDS (planar, strided access -> conflict-free b32 reads); z and
// the running min-dist pd live in registers (only 32 values -> no AGPR
// shuttling, the failure mode of rounds 2-5). The serial tail is LDS-only:
// winner centroid x,y read from s_x/s_y, z from a per-wave candidate slot.
// Exact reference semantics: dist = min(dist, (x-cx)^2+(y-cy)^2+(z-cz)^2)
// (fp32, no FMA, (xx+yy)+zz association), argmax with FIRST-ORIGINAL-INDEX
// tie-break (fast path = unique max; rare uniform path min-reduces indices).
// -----------------------------------------------------------------------------
__global__ __launch_bounds__(NTHREADS, 4) void fps_kernel(
    const float* __restrict__ xyz, int* __restrict__ sorted_idx)
{
    __shared__ float s_x[NPTS];                      // 64 KiB
    __shared__ float s_y[NPTS];                      // 64 KiB
    __shared__ unsigned s_bitmap[NPTS / 32];         // 2 KiB
    __shared__ unsigned long long s_slot[2][16];     // parity {val_bits, idx}
    __shared__ float s_zc[2][16];                    // parity candidate z
    __shared__ int s_wt[NTHREADS / 64];              // tail scan totals

    const int tid  = threadIdx.x;
    const int lane = tid & 63;
    const int wid  = tid >> 6;
    const int b    = blockIdx.x;

    if (tid < NPTS / 32) s_bitmap[tid] = 0u;

    const float* xb = xyz + (size_t)b * NPTS * 3;

    // stage x,y into LDS; z into registers (strided assignment)
    float pz_[PPT], pd[PPT];
    #pragma unroll
    for (int k = 0; k < PPT; ++k) {
        int g = (k << 10) + tid;
        s_x[g]  = xb[3 * g + 0];
        s_y[g]  = xb[3 * g + 1];
        pz_[k]  = xb[3 * g + 2];
        pd[k]   = 1e10f;          // BIG, matches reference init
    }
    // z becomes an asm output: cannot be rematerialized from memory
    #pragma unroll
    for (int k = 0; k < PPT; ++k) asm volatile("" : "+v"(pz_[k]));

    // initial farthest = index 0
    float cx = xb[0], cy = xb[1], cz = xb[2];
    if (tid == 0) s_bitmap[0] = 1u;
    __syncthreads();

    for (int s = 0; s < NSAMP - 1; ++s) {
        const int p = s & 1;

        // --- phase A: exact distance update + per-thread argmax ---
        float bv = -1.0f;
        int   bk = 0;
        #pragma unroll
        for (int k = 0; k < PPT; ++k) {
            float dx = __fsub_rn(s_x[(k << 10) + tid], cx);
            float dy = __fsub_rn(s_y[(k << 10) + tid], cy);
            float dz = __fsub_rn(pz_[k], cz);
            float d  = __fadd_rn(__fadd_rn(__fmul_rn(dx, dx), __fmul_rn(dy, dy)),
                                 __fmul_rn(dz, dz));
            float nd = fminf(pd[k], d);
            pd[k] = nd;
            if (nd > bv) { bv = nd; bk = k; }   // strict > keeps smallest k (= smallest idx)
        }

        // --- phase B: wave max (value-only DPP), candidate via ballot ---
        float wv = bv;
        wv = fmaxf(wv, dpp_movf<0x111, 0xF>(wv));   // row_shr:1
        wv = fmaxf(wv, dpp_movf<0x112, 0xF>(wv));   // row_shr:2
        wv = fmaxf(wv, dpp_movf<0x114, 0xF>(wv));   // row_shr:4
        wv = fmaxf(wv, dpp_movf<0x118, 0xF>(wv));   // row_shr:8
        wv = fmaxf(wv, dpp_movf<0x142, 0xA>(wv));   // row_bcast:15
        wv = fmaxf(wv, dpp_movf<0x143, 0xC>(wv));   // row_bcast:31 -> lane 63
        int   m_bits = __builtin_amdgcn_readlane(__float_as_int(wv), 63);
        float m_w    = __int_as_float(m_bits);
        int myidx = (bk << 10) + tid;               // this thread's candidate (min idx of its ties)
        unsigned long long mk = __ballot(bv == m_w);
        int sl, cidx;
        if (__popcll(mk) == 1) {                    // unique max lane (uniform branch)
            sl   = __ffsll(mk) - 1;
            cidx = __builtin_amdgcn_readlane(myidx, sl);
        } else {                                    // rare: exact min-orig-index over ties
            unsigned long long t = mk;
            cidx = 0x7FFFFFFF; sl = 0;
            while (t) {
                int l = __ffsll(t) - 1; t &= t - 1;
                int c2 = __builtin_amdgcn_readlane(myidx, l);
                if (c2 < cidx) { cidx = c2; sl = l; }
            }
        }
        if (lane == sl) {
            // extract z[bk] via static select chain (no runtime indexing)
            float zc = pz_[0];
            #pragma unroll
            for (int k = 1; k < PPT; ++k) if (bk == k) zc = pz_[k];
            s_slot[p][wid] = ((unsigned long long)(unsigned)m_bits << 32) |
                             (unsigned)cidx;
            s_zc[p][wid] = zc;
        }

        __syncthreads();   // the ONLY barrier per iteration

        // --- phase C: reduce the 16 wave slots (replicated in each 16-lane row) ---
        unsigned long long key = s_slot[p][lane & 15];
        float cv = __int_as_float((int)(key >> 32));
        int   ci = (int)(unsigned)key;
        float rv = cv;
        rv = fmaxf(rv, dpp_movf<0x111, 0xF>(rv));
        rv = fmaxf(rv, dpp_movf<0x112, 0xF>(rv));
        rv = fmaxf(rv, dpp_movf<0x114, 0xF>(rv));
        rv = fmaxf(rv, dpp_movf<0x118, 0xF>(rv));   // lane 15 of each row = max
        int   gm_bits = __builtin_amdgcn_readlane(__float_as_int(rv), 15);
        float gm      = __int_as_float(gm_bits);
        unsigned long long m2 = __ballot(cv == gm); // 4 replicated 16-bit groups
        int w, g;
        if (__popcll(m2) == 4) {                    // single winning wave (uniform)
            w = __ffsll(m2) - 1;                    // in 0..15
            g = __builtin_amdgcn_readlane(ci, w);
        } else {                                    // rare: min orig index across waves
            unsigned long long t = m2 & 0xFFFFull;
            g = 0x7FFFFFFF; w = 0;
            while (t) {
                int l = __ffsll(t) - 1; t &= t - 1;
                int g2 = __builtin_amdgcn_readlane(ci, l);
                if (g2 < g) { g = g2; w = l; }
            }
        }

        // centroid for next iteration: all from LDS (no global access)
        cx = s_x[g];
        cy = s_y[g];
        cz = s_zc[p][w];

        if (tid == 0) s_bitmap[g >> 5] |= (1u << (g & 31));
    }
    __syncthreads();

    // --- tail: bitmap -> ascending index list via block prefix scan ---
    const int nwords = NPTS / 32;   // 512
    unsigned word = (tid < nwords) ? s_bitmap[tid] : 0u;
    int cnt = __popc(word);
    int inc = cnt;
    #pragma unroll
    for (int off = 1; off < 64; off <<= 1) {
        int n = __shfl_up(inc, off);
        if (lane >= off) inc += n;
    }
    if (lane == 63) s_wt[wid] = inc;
    __syncthreads();
    int base = inc - cnt;
    for (int w = 0; w < wid; ++w) base += s_wt[w];
    int* sb = sorted_idx + (size_t)b * NSAMP;
    int pos = base;
    unsigned wmask = word;
    while (wmask) {
        int k = __ffs(wmask) - 1;
        wmask &= wmask - 1;
        sb[pos++] = tid * 32 + k;
    }
}

// -----------------------------------------------------------------------------
// Gather kernel: one wave per sampled row.
//   out0 = new_xyz [B,S,3]; out1 = concat(xyz, points) [B,S,1,131]; out2 [B,S,128]
// -----------------------------------------------------------------------------
__global__ void gather_kernel(
    const float* __restrict__ xyz, const float* __restrict__ points,
    const float* __restrict__ pres, const int* __restrict__ sorted_idx,
    float* __restrict__ out0, float* __restrict__ out1, float* __restrict__ out2)
{
    int gw   = (int)((blockIdx.x * (unsigned)blockDim.x + threadIdx.x) >> 6);
    int lane = threadIdx.x & 63;
    if (gw >= BATCH * NSAMP) return;
    int b = gw >> 12;               // NSAMP == 4096
    int i = sorted_idx[gw];

    const float* xs = xyz    + ((size_t)b * NPTS + i) * 3;
    const float* ps = points + ((size_t)b * NPTS + i) * 128;
    const float* rs = pres   + ((size_t)b * NPTS + i) * 128;

    if (lane < 3) out0[(size_t)gw * 3 + lane] = xs[lane];

    float* o1 = out1 + (size_t)gw * 131;
    #pragma unroll
    for (int j = 0; j < 3; ++j) {
        int c = lane + 64 * j;
        if (c < 131) o1[c] = (c < 3) ? xs[c] : ps[c - 3];
    }

    const float2* r2 = (const float2*)rs;
    float2* o2 = (float2*)(out2 + (size_t)gw * 128);
    o2[lane] = r2[lane];
}

extern "C" void kernel_launch(void* const* d_in, const int* in_sizes, int n_in,
                              void* d_out, int out_size, void* d_ws, size_t ws_size,
                              hipStream_t stream)
{
    const float* xyz    = (const float*)d_in[0];
    const float* points = (const float*)d_in[1];
    const float* pres   = (const float*)d_in[2];

    float* out  = (float*)d_out;
    float* out0 = out;                                     // B*S*3
    float* out1 = out0 + (size_t)BATCH * NSAMP * 3;        // B*S*131
    float* out2 = out1 + (size_t)BATCH * NSAMP * 131;      // B*S*128

    int* sorted = (int*)d_ws;   // B*S ints = 256 KiB scratch

    fps_kernel<<<BATCH, NTHREADS, 0, stream>>>(xyz, sorted);

    int total_threads = BATCH * NSAMP * 64;   // one wave per sampled row
    int threads = 256;
    int blocks  = total_threads / threads;
    gather_kernel<<<blocks, threads, 0, stream>>>(xyz, points, pres, sorted,
                                                  out0, out1, out2);
}

// Round 7
// 5288.874 us; speedup vs baseline: 1.5251x; 1.5251x over previous
//
#include <hip/hip_runtime.h>

// Problem constants (from setup_inputs: B=16, N=16384, D=128, S=N/4)
#define BATCH    16
#define NPTS     16384
#define NSAMP    4096
#define NTHREADS 1024
#define PPT      16
#define NWAVE    16

// DPP move helper (disabled lanes keep old value = own value)
template<int CTRL, int RM>
__device__ __forceinline__ float dpp_movf(float v) {
    return __int_as_float(__builtin_amdgcn_update_dpp(
        __float_as_int(v), __float_as_int(v), CTRL, RM, 0xF, false));
}

__device__ __forceinline__ float wave_max64(float v) {
    v = fmaxf(v, dpp_movf<0x111, 0xF>(v));   // row_shr:1
    v = fmaxf(v, dpp_movf<0x112, 0xF>(v));   // row_shr:2
    v = fmaxf(v, dpp_movf<0x114, 0xF>(v));   // row_shr:4
    v = fmaxf(v, dpp_movf<0x118, 0xF>(v));   // row_shr:8
    v = fmaxf(v, dpp_movf<0x142, 0xA>(v));   // row_bcast:15
    v = fmaxf(v, dpp_movf<0x143, 0xC>(v));   // row_bcast:31 -> lane 63 = max
    return v;
}
__device__ __forceinline__ float wave_min64(float v) {
    v = fminf(v, dpp_movf<0x111, 0xF>(v));
    v = fminf(v, dpp_movf<0x112, 0xF>(v));
    v = fminf(v, dpp_movf<0x114, 0xF>(v));
    v = fminf(v, dpp_movf<0x118, 0xF>(v));
    v = fminf(v, dpp_movf<0x142, 0xA>(v));
    v = fminf(v, dpp_movf<0x143, 0xC>(v));
    return v;
}

// spread 6 bits to every 3rd position (Morton interleave component)
__device__ __forceinline__ unsigned spread6(unsigned v) {
    return (v & 1u) | ((v & 2u) << 2) | ((v & 4u) << 4) |
           ((v & 8u) << 6) | ((v & 16u) << 8) | ((v & 32u) << 10);
}

// -----------------------------------------------------------------------------
// FPS kernel with EXACT wave-level spatial pruning.
//  - Morton-bucket the 16384 points into 16 spatially-coherent wave groups
//    (bitonic sort in LDS), then re-sort each wave segment by ORIGINAL index
//    so lane/k order == original-index order (exact first-index tie-break).
//  - Per iteration, wave w skips the entire distance update when
//    0.9999*mindist(c, box_w)^2 >= gub_w (cached exact wave max of pd):
//    then d(c,p) >= gub_w >= pd[p] for all its points -> provable no-op,
//    cached (max, argmax-orig-idx) stays exact. No replay needed.
//  - Active waves run the exact reference update: dist=min(dist,(dx2+dy2)+dz2)
//    fp32 no-FMA, argmax first-original-index.
// -----------------------------------------------------------------------------
__global__ __launch_bounds__(NTHREADS, 4) void fps_kernel(
    const float* __restrict__ xyz, int* __restrict__ sorted_idx)
{
    __shared__ unsigned s_key[NPTS];                 // 64 KiB: cell<<14 | orig
    __shared__ unsigned s_bitmap[NPTS / 32];         // 2 KiB
    __shared__ unsigned long long s_slot[2][NWAVE];  // parity {max_bits, orig_idx}
    __shared__ float s_bb[NWAVE][6];                 // bbox staging
    __shared__ int s_wt[NWAVE];                      // tail scan totals

    const int tid  = threadIdx.x;
    const int lane = tid & 63;
    const int wid  = tid >> 6;
    const int b    = blockIdx.x;

    if (tid < NPTS / 32) s_bitmap[tid] = 0u;

    const float* xb = xyz + (size_t)b * NPTS * 3;

    // ---- global bbox (for Morton quantization) ----
    float mnx = 1e30f, mny = 1e30f, mnz = 1e30f;
    float mxx = -1e30f, mxy = -1e30f, mxz = -1e30f;
    {
        #pragma unroll
        for (int k = 0; k < PPT; ++k) {
            int i = (tid << 4) + k;
            float x = xb[3 * i], y = xb[3 * i + 1], z = xb[3 * i + 2];
            mnx = fminf(mnx, x); mxx = fmaxf(mxx, x);
            mny = fminf(mny, y); mxy = fmaxf(mxy, y);
            mnz = fminf(mnz, z); mxz = fmaxf(mxz, z);
        }
        mnx = wave_min64(mnx); mxx = wave_max64(mxx);
        mny = wave_min64(mny); mxy = wave_max64(mxy);
        mnz = wave_min64(mnz); mxz = wave_max64(mxz);
        if (lane == 63) {
            s_bb[wid][0] = mnx; s_bb[wid][1] = mny; s_bb[wid][2] = mnz;
            s_bb[wid][3] = mxx; s_bb[wid][4] = mxy; s_bb[wid][5] = mxz;
        }
    }
    __syncthreads();
    float glx = s_bb[0][0], gly = s_bb[0][1], glz = s_bb[0][2];
    float ghx = s_bb[0][3], ghy = s_bb[0][4], ghz = s_bb[0][5];
    for (int w = 1; w < NWAVE; ++w) {
        glx = fminf(glx, s_bb[w][0]); gly = fminf(gly, s_bb[w][1]);
        glz = fminf(glz, s_bb[w][2]);
        ghx = fmaxf(ghx, s_bb[w][3]); ghy = fmaxf(ghy, s_bb[w][4]);
        ghz = fmaxf(ghz, s_bb[w][5]);
    }
    float qsx = 63.999f / fmaxf(ghx - glx, 1e-20f);
    float qsy = 63.999f / fmaxf(ghy - gly, 1e-20f);
    float qsz = 63.999f / fmaxf(ghz - glz, 1e-20f);

    // ---- Morton keys ----
    __syncthreads();
    #pragma unroll
    for (int k = 0; k < PPT; ++k) {
        int i = (tid << 4) + k;
        int qx = min(max((int)((xb[3 * i]     - glx) * qsx), 0), 63);
        int qy = min(max((int)((xb[3 * i + 1] - gly) * qsy), 0), 63);
        int qz = min(max((int)((xb[3 * i + 2] - glz) * qsz), 0), 63);
        unsigned cell = spread6((unsigned)qx) | (spread6((unsigned)qy) << 1) |
                        (spread6((unsigned)qz) << 2);
        s_key[i] = (cell << 14) | (unsigned)i;
    }

    // ---- bitonic sort #1 by Morton key (groups points spatially) ----
    for (int k = 2; k <= NPTS; k <<= 1) {
        for (int j = k >> 1; j > 0; j >>= 1) {
            __syncthreads();
            #pragma unroll
            for (int m = 0; m < PPT; ++m) {
                int i = (m << 10) | tid;
                int l = i ^ j;
                if (l > i) {
                    unsigned a = s_key[i], c2 = s_key[l];
                    bool up = ((i & k) == 0);
                    if ((a > c2) == up) { s_key[i] = c2; s_key[l] = a; }
                }
            }
        }
    }
    __syncthreads();
    // ---- re-key: group(4b) | orig(14b); sort #2 -> per-wave-segment orig asc ----
    #pragma unroll
    for (int m = 0; m < PPT; ++m) {
        int p = (m << 10) | tid;
        s_key[p] = ((unsigned)(p >> 10) << 14) | (s_key[p] & 0x3FFFu);
    }
    for (int k = 2; k <= NPTS; k <<= 1) {
        for (int j = k >> 1; j > 0; j >>= 1) {
            __syncthreads();
            #pragma unroll
            for (int m = 0; m < PPT; ++m) {
                int i = (m << 10) | tid;
                int l = i ^ j;
                if (l > i) {
                    unsigned a = s_key[i], c2 = s_key[l];
                    bool up = ((i & k) == 0);
                    if ((a > c2) == up) { s_key[i] = c2; s_key[l] = a; }
                }
            }
        }
    }
    __syncthreads();

    // ---- gather coords per new ownership; init pd ----
    float px[PPT], py[PPT], pz[PPT], pd[PPT];
    #pragma unroll
    for (int k = 0; k < PPT; ++k) {
        int orig = (int)(s_key[(tid << 4) + k] & 0x3FFFu);
        px[k] = xb[3 * orig];
        py[k] = xb[3 * orig + 1];
        pz[k] = xb[3 * orig + 2];
        pd[k] = 1e10f;
    }

    // ---- per-wave bbox (registers, uniform) ----
    float wlx = 1e30f, wly = 1e30f, wlz = 1e30f;
    float whx = -1e30f, why_ = -1e30f, whz = -1e30f;
    #pragma unroll
    for (int k = 0; k < PPT; ++k) {
        wlx = fminf(wlx, px[k]); whx = fmaxf(whx, px[k]);
        wly = fminf(wly, py[k]); why_ = fmaxf(why_, py[k]);
        wlz = fminf(wlz, pz[k]); whz = fmaxf(whz, pz[k]);
    }
    wlx = wave_min64(wlx); whx = wave_max64(whx);
    wly = wave_min64(wly); why_ = wave_max64(why_);
    wlz = wave_min64(wlz); whz = wave_max64(whz);
    wlx = __int_as_float(__builtin_amdgcn_readlane(__float_as_int(wlx), 63));
    wly = __int_as_float(__builtin_amdgcn_readlane(__float_as_int(wly), 63));
    wlz = __int_as_float(__builtin_amdgcn_readlane(__float_as_int(wlz), 63));
    whx = __int_as_float(__builtin_amdgcn_readlane(__float_as_int(whx), 63));
    why_ = __int_as_float(__builtin_amdgcn_readlane(__float_as_int(why_), 63));
    whz = __int_as_float(__builtin_amdgcn_readlane(__float_as_int(whz), 63));

    // ---- main FPS loop ----
    float cx = xb[0], cy = xb[1], cz = xb[2];   // initial farthest = index 0
    if (tid == 0) s_bitmap[0] = 1u;

    float    gubf     = 1e10f;      // cached exact wave max of pd (valid after iter 0)
    unsigned gub_bits = __float_as_uint(1e10f);
    unsigned gidx     = 0u;         // cached wave argmax (orig idx)
    __syncthreads();

    for (int s = 0; s < NSAMP - 1; ++s) {
        // conservative lower bound on dist^2 from c to wave bbox
        float txc = fmaxf(fmaxf(__fsub_rn(wlx, cx), __fsub_rn(cx, whx)), 0.0f);
        float tyc = fmaxf(fmaxf(__fsub_rn(wly, cy), __fsub_rn(cy, why_)), 0.0f);
        float tzc = fmaxf(fmaxf(__fsub_rn(wlz, cz), __fsub_rn(cz, whz)), 0.0f);
        float md2 = 0.9999f * (__fadd_rn(__fadd_rn(__fmul_rn(txc, txc),
                                                   __fmul_rn(tyc, tyc)),
                                         __fmul_rn(tzc, tzc)));
        if (md2 < gubf) {   // wave-uniform branch: must update
            float bv = -1.0f;
            int   bk = 0;
            #pragma unroll
            for (int k = 0; k < PPT; ++k) {
                float dx = __fsub_rn(px[k], cx);
                float dy = __fsub_rn(py[k], cy);
                float dz = __fsub_rn(pz[k], cz);
                float d  = __fadd_rn(__fadd_rn(__fmul_rn(dx, dx),
                                               __fmul_rn(dy, dy)),
                                     __fmul_rn(dz, dz));
                float nd = fminf(pd[k], d);
                pd[k] = nd;
                if (nd > bv) { bv = nd; bk = k; }  // strict >: first k = min orig
            }
            float wv = wave_max64(bv);
            int   mb = __builtin_amdgcn_readlane(__float_as_int(wv), 63);
            float mw = __int_as_float(mb);
            unsigned long long mk = __ballot(bv == mw);
            int sl = __ffsll(mk) - 1;              // min lane = min orig (sorted)
            int o  = 0;
            if (lane == sl) o = (int)(s_key[(tid << 4) + bk] & 0x3FFFu);
            o = __builtin_amdgcn_readlane(o, sl);
            gubf = mw; gub_bits = (unsigned)mb; gidx = (unsigned)o;
        }
        if (lane == 0)
            s_slot[s & 1][wid] =
                ((unsigned long long)gub_bits << 32) | gidx;

        __syncthreads();   // the ONLY barrier per iteration

        // ---- global argmax over the 16 wave slots ----
        unsigned long long key = s_slot[s & 1][lane & 15];
        float cv = __int_as_float((int)(key >> 32));
        unsigned ci = (unsigned)key;
        float rv = cv;
        rv = fmaxf(rv, dpp_movf<0x111, 0xF>(rv));
        rv = fmaxf(rv, dpp_movf<0x112, 0xF>(rv));
        rv = fmaxf(rv, dpp_movf<0x114, 0xF>(rv));
        rv = fmaxf(rv, dpp_movf<0x118, 0xF>(rv));  // lane 15 of row = max
        int   gmb = __builtin_amdgcn_readlane(__float_as_int(rv), 15);
        float gm  = __int_as_float(gmb);
        unsigned long long m2 = __ballot(cv == gm);
        int g;
        if (__popcll(m2) == 4) {                   // unique winning wave
            int w = __ffsll(m2) - 1;
            g = __builtin_amdgcn_readlane((int)ci, w);
        } else {                                   // ties: exact min orig idx
            unsigned long long t = m2 & 0xFFFFull;
            g = 0x7FFFFFFF;
            while (t) {
                int l = __ffsll(t) - 1; t &= t - 1;
                int g2 = __builtin_amdgcn_readlane((int)ci, l);
                g = min(g, g2);
            }
        }

        cx = xb[3 * g];                            // uniform scalar loads (L2)
        cy = xb[3 * g + 1];
        cz = xb[3 * g + 2];

        if (tid == 0) s_bitmap[g >> 5] |= (1u << (g & 31));
    }
    __syncthreads();

    // ---- tail: bitmap -> ascending index list via block prefix scan ----
    const int nwords = NPTS / 32;   // 512
    unsigned word = (tid < nwords) ? s_bitmap[tid] : 0u;
    int cnt = __popc(word);
    int inc = cnt;
    #pragma unroll
    for (int off = 1; off < 64; off <<= 1) {
        int n = __shfl_up(inc, off);
        if (lane >= off) inc += n;
    }
    if (lane == 63) s_wt[wid] = inc;
    __syncthreads();
    int base = inc - cnt;
    for (int w = 0; w < wid; ++w) base += s_wt[w];
    int* sb = sorted_idx + (size_t)b * NSAMP;
    int pos = base;
    unsigned wmask = word;
    while (wmask) {
        int k = __ffs(wmask) - 1;
        wmask &= wmask - 1;
        sb[pos++] = tid * 32 + k;
    }
}

// -----------------------------------------------------------------------------
// Gather kernel: one wave per sampled row.
//   out0 = new_xyz [B,S,3]; out1 = concat(xyz, points) [B,S,1,131]; out2 [B,S,128]
// -----------------------------------------------------------------------------
__global__ void gather_kernel(
    const float* __restrict__ xyz, const float* __restrict__ points,
    const float* __restrict__ pres, const int* __restrict__ sorted_idx,
    float* __restrict__ out0, float* __restrict__ out1, float* __restrict__ out2)
{
    int gw   = (int)((blockIdx.x * (unsigned)blockDim.x + threadIdx.x) >> 6);
    int lane = threadIdx.x & 63;
    if (gw >= BATCH * NSAMP) return;
    int b = gw >> 12;               // NSAMP == 4096
    int i = sorted_idx[gw];

    const float* xs = xyz    + ((size_t)b * NPTS + i) * 3;
    const float* ps = points + ((size_t)b * NPTS + i) * 128;
    const float* rs = pres   + ((size_t)b * NPTS + i) * 128;

    if (lane < 3) out0[(size_t)gw * 3 + lane] = xs[lane];

    float* o1 = out1 + (size_t)gw * 131;
    #pragma unroll
    for (int j = 0; j < 3; ++j) {
        int c = lane + 64 * j;
        if (c < 131) o1[c] = (c < 3) ? xs[c] : ps[c - 3];
    }

    const float2* r2 = (const float2*)rs;
    float2* o2 = (float2*)(out2 + (size_t)gw * 128);
    o2[lane] = r2[lane];
}

extern "C" void kernel_launch(void* const* d_in, const int* in_sizes, int n_in,
                              void* d_out, int out_size, void* d_ws, size_t ws_size,
                              hipStream_t stream)
{
    const float* xyz    = (const float*)d_in[0];
    const float* points = (const float*)d_in[1];
    const float* pres   = (const float*)d_in[2];

    float* out  = (float*)d_out;
    float* out0 = out;                                     // B*S*3
    float* out1 = out0 + (size_t)BATCH * NSAMP * 3;        // B*S*131
    float* out2 = out1 + (size_t)BATCH * NSAMP * 131;      // B*S*128

    int* sorted = (int*)d_ws;   // B*S ints = 256 KiB scratch

    fps_kernel<<<BATCH, NTHREADS, 0, stream>>>(xyz, sorted);

    int total_threads = BATCH * NSAMP * 64;   // one wave per sampled row
    int threads = 256;
    int blocks  = total_threads / threads;
    gather_kernel<<<blocks, threads, 0, stream>>>(xyz, points, pres, sorted,
                                                  out0, out1, out2);
}